// Round 4
// baseline (394.758 us; speedup 1.0000x reference)
//
#include <hip/hip_runtime.h>
#include <math.h>

// Problem constants
#define T_DIM 1024
#define N_DIM 8192
#define M_TOT (T_DIM * N_DIM)      // 8,388,608
#define NVEC  (M_TOT / 4)          // 2,097,152 float4 elements
#define NV4   (N_DIM / 4)          // 2048 float4 per row
#define L_CHUNK 8
#define C_CHUNKS 128               // T_DIM / L_CHUNK

#define STREAM_GRID 2048
#define STRIDE (STREAM_GRID * 256) // 524,288 threads; NVEC = 4 * STRIDE exactly

#define kGAMMA 0.99f
#define kGLAM  (0.99f * 0.95f)

// ws layout (25.2 MB):
//   [0, 64)        acc doubles: 0=sum g, 1=sum g^2, 2=action sum, 3=value sum,
//                  4=entropy sum
//   [64, 68)       done counter (uint)
//   +512           b16 [T][N] ushort (16 MB) -- k_gae overwrites with gae16
//   +512+16MB      A [C][N] float (4 MB)     -- k_ginc overwrites with g_in
//   +512+20MB      B [C][N] float (4 MB)

__device__ __forceinline__ unsigned short f2bf(float f) {
    unsigned int u = __float_as_uint(f);
    u += 0x7fffu + ((u >> 16) & 1u);        // round-to-nearest-even
    return (unsigned short)(u >> 16);
}
__device__ __forceinline__ float bf2f(unsigned short h) {
    return __uint_as_float(((unsigned int)h) << 16);
}

// ---------------------------------------------------------------------------
// P1: streaming elementwise, fixed trip count, all loads batched up front.
// b_t = (r + g*m*v_next - v) * bb stored bf16 with a-bit (m*bb!=0) in LSB.
// Block 0 also zeros the accumulators (nothing reads them until k_gae).
__global__ __launch_bounds__(256, 4) void k_prep(
    const float4* __restrict__ r4,
    const float4* __restrict__ m4,     // (T+1) rows
    const float4* __restrict__ bm4,    // (T+1) rows
    const float4* __restrict__ vp4,    // (T+1) rows
    const float4* __restrict__ lv4,    // (N,)
    ushort4* __restrict__ b16,
    double* __restrict__ acc,
    unsigned int* __restrict__ done)
{
    if (blockIdx.x == 0) {
        if (threadIdx.x < 8) acc[threadIdx.x] = 0.0;
        if (threadIdx.x == 8) *done = 0u;
    }
    const int tid = blockIdx.x * 256 + threadIdx.x;

    float4 R[4], V[4], M[4], B[4], VN[4];
    #pragma unroll
    for (int k = 0; k < 4; ++k) {
        const int i = tid + k * STRIDE;
        R[k] = r4[i];
        V[k] = vp4[i];
        M[k] = m4[i + NV4];
        B[k] = bm4[i + NV4];
    }
    #pragma unroll
    for (int k = 0; k < 4; ++k) {
        const int i = tid + k * STRIDE;
        const int t = i >> 11;
        VN[k] = (t == T_DIM - 1) ? lv4[i & (NV4 - 1)] : vp4[i + NV4];
    }

    #pragma unroll
    for (int k = 0; k < 4; ++k) {
        ushort4 o;
        {
            float b = (fmaf(kGAMMA * M[k].x, VN[k].x, R[k].x) - V[k].x) * B[k].x;
            o.x = (unsigned short)((f2bf(b) & 0xFFFEu) | ((M[k].x * B[k].x > 0.5f) ? 1u : 0u));
        }
        {
            float b = (fmaf(kGAMMA * M[k].y, VN[k].y, R[k].y) - V[k].y) * B[k].y;
            o.y = (unsigned short)((f2bf(b) & 0xFFFEu) | ((M[k].y * B[k].y > 0.5f) ? 1u : 0u));
        }
        {
            float b = (fmaf(kGAMMA * M[k].z, VN[k].z, R[k].z) - V[k].z) * B[k].z;
            o.z = (unsigned short)((f2bf(b) & 0xFFFEu) | ((M[k].z * B[k].z > 0.5f) ? 1u : 0u));
        }
        {
            float b = (fmaf(kGAMMA * M[k].w, VN[k].w, R[k].w) - V[k].w) * B[k].w;
            o.w = (unsigned short)((f2bf(b) & 0xFFFEu) | ((M[k].w * B[k].w > 0.5f) ? 1u : 0u));
        }
        b16[tid + k * STRIDE] = o;
    }
}

// ---------------------------------------------------------------------------
// P2: compose per-chunk affine maps (A,B) over L=8 steps from b16.
__device__ __forceinline__ void stepAB(float& A, float& B, unsigned short h) {
    const float bf = bf2f(h);
    const float a  = (h & 1u) ? kGLAM : 0.0f;
    A = a * A;
    B = fmaf(a, B, bf);
}

__global__ __launch_bounds__(256) void k_chunk(
    const ushort4* __restrict__ b16,
    float4* __restrict__ A_out,
    float4* __restrict__ B_out)
{
    const int g = blockIdx.x * 256 + threadIdx.x;   // 0 .. C*NV4-1
    const int j = g & (NV4 - 1);
    const int c = g >> 11;
    const int t0 = c * L_CHUNK;

    ushort4 bq[L_CHUNK];
    #pragma unroll
    for (int i = 0; i < L_CHUNK; ++i) bq[i] = b16[(t0 + i) * NV4 + j];

    float4 Aa = make_float4(1.f, 1.f, 1.f, 1.f);
    float4 Bb = make_float4(0.f, 0.f, 0.f, 0.f);
    #pragma unroll
    for (int i = L_CHUNK - 1; i >= 0; --i) {
        stepAB(Aa.x, Bb.x, bq[i].x);
        stepAB(Aa.y, Bb.y, bq[i].y);
        stepAB(Aa.z, Bb.z, bq[i].z);
        stepAB(Aa.w, Bb.w, bq[i].w);
    }
    A_out[c * NV4 + j] = Aa;
    B_out[c * NV4 + j] = Bb;
}

// ---------------------------------------------------------------------------
// P3: per-env serial scan over the 128 chunk maps; writes each chunk's
// incoming gae. g_in ALIASES A (load batch, then store over it).
__global__ __launch_bounds__(256) void k_ginc(
    const float* __restrict__ A_in,
    const float* __restrict__ B_in,
    float* __restrict__ g_in)          // aliases A_in
{
    const int n = blockIdx.x * 256 + threadIdx.x;   // 0..N-1
    float g = 0.0f;
    constexpr int PB = 16;
    for (int cb = C_CHUNKS - PB; cb >= 0; cb -= PB) {
        float Ar[PB], Br[PB];
        #pragma unroll
        for (int i = 0; i < PB; ++i) {
            Ar[i] = A_in[(cb + i) * N_DIM + n];
            Br[i] = B_in[(cb + i) * N_DIM + n];
        }
        #pragma unroll
        for (int i = PB - 1; i >= 0; --i) {
            g_in[(cb + i) * N_DIM + n] = g;
            g = fmaf(Ar[i], g, Br[i]);
        }
    }
}

// ---------------------------------------------------------------------------
// P4: recompute gae per element (2-op chain on b16), write gae16 in place,
// fuse value loss (reads vp, nv) and sum/sum2 of gae.
__device__ __forceinline__ void gae_comp(float& gae, unsigned short h,
                                         float v, float nvv,
                                         float& sg, float& sg2, float& v_s) {
    const float bf = bf2f(h);
    const float a  = (h & 1u) ? kGLAM : 0.0f;
    gae = fmaf(a, gae, bf);
    sg += gae;
    sg2 = fmaf(gae, gae, sg2);
    const float q  = nvv - v;
    const float e1 = q - gae;
    const float e2 = fminf(fmaxf(q, -0.2f), 0.2f) - gae;
    v_s += fmaxf(e1 * e1, e2 * e2);
}

__global__ __launch_bounds__(256) void k_gae(
    ushort4* __restrict__ bg16,        // in: b16, out: gae16
    const float4* __restrict__ g_in4,
    const float4* __restrict__ vp4,
    const float4* __restrict__ nv4,
    double* __restrict__ acc)
{
    const int g = blockIdx.x * 256 + threadIdx.x;   // 0 .. C*NV4-1
    const int j = g & (NV4 - 1);
    const int c = g >> 11;
    const int t0 = c * L_CHUNK;

    ushort4 bq[L_CHUNK];
    float4 vv[L_CHUNK], nn[L_CHUNK];
    #pragma unroll
    for (int i = 0; i < L_CHUNK; ++i) {
        const int idx = (t0 + i) * NV4 + j;
        bq[i] = bg16[idx];
        vv[i] = vp4[idx];
        nn[i] = nv4[idx];
    }

    float4 gae = g_in4[c * NV4 + j];
    float sg = 0.f, sg2 = 0.f, v_s = 0.f;
    #pragma unroll
    for (int i = L_CHUNK - 1; i >= 0; --i) {
        gae_comp(gae.x, bq[i].x, vv[i].x, nn[i].x, sg, sg2, v_s);
        gae_comp(gae.y, bq[i].y, vv[i].y, nn[i].y, sg, sg2, v_s);
        gae_comp(gae.z, bq[i].z, vv[i].z, nn[i].z, sg, sg2, v_s);
        gae_comp(gae.w, bq[i].w, vv[i].w, nn[i].w, sg, sg2, v_s);
        ushort4 o;
        o.x = f2bf(gae.x); o.y = f2bf(gae.y); o.z = f2bf(gae.z); o.w = f2bf(gae.w);
        bg16[(t0 + i) * NV4 + j] = o;
    }

    double d0 = (double)sg, d1 = (double)sg2, d2 = (double)v_s;
    #pragma unroll
    for (int off = 32; off > 0; off >>= 1) {
        d0 += __shfl_down(d0, off, 64);
        d1 += __shfl_down(d1, off, 64);
        d2 += __shfl_down(d2, off, 64);
    }
    __shared__ double sh[3][4];
    const int wid = threadIdx.x >> 6, lane = threadIdx.x & 63;
    if (lane == 0) { sh[0][wid] = d0; sh[1][wid] = d1; sh[2][wid] = d2; }
    __syncthreads();
    if (threadIdx.x == 0) {
        double t0s = 0, t1s = 0, t2s = 0;
        #pragma unroll
        for (int w = 0; w < 4; ++w) { t0s += sh[0][w]; t1s += sh[1][w]; t2s += sh[2][w]; }
        atomicAdd(&acc[0], t0s);
        atomicAdd(&acc[1], t1s);
        atomicAdd(&acc[3], t2s);
    }
}

// ---------------------------------------------------------------------------
// P5: action loss + entropy; fixed trip count, batched loads; inline stats;
// last block computes the final scalar loss.
__global__ __launch_bounds__(256, 4) void k_loss(
    const ushort4* __restrict__ gae16,
    const float4* __restrict__ lp4,
    const float4* __restrict__ plp4,
    const float4* __restrict__ ent4,
    double* __restrict__ acc,
    unsigned int* __restrict__ done,
    float* __restrict__ out)
{
    const int tid = blockIdx.x * 256 + threadIdx.x;

    ushort4 G[4];
    float4  L[4], P[4], E[4];
    #pragma unroll
    for (int k = 0; k < 4; ++k) {
        const int i = tid + k * STRIDE;
        G[k] = gae16[i];
        L[k] = lp4[i];
        P[k] = plp4[i];
        E[k] = ent4[i];
    }

    // stats from acc[0..1] (written by k_gae, stream-ordered before us)
    const double Md   = (double)M_TOT;
    const double sum  = acc[0], sum2 = acc[1];
    const float  mu   = (float)(sum / Md);
    double var = (sum2 - sum * sum / Md) / (Md - 1.0);
    if (var < 0.0) var = 0.0;
    const float invs = (float)(1.0 / (sqrt(var) + 1e-5));

    float a_s = 0.f, e_s = 0.f;
    #pragma unroll
    for (int k = 0; k < 4; ++k) {
        const float gs[4] = {bf2f(G[k].x), bf2f(G[k].y), bf2f(G[k].z), bf2f(G[k].w)};
        const float ls[4] = {L[k].x, L[k].y, L[k].z, L[k].w};
        const float ps[4] = {P[k].x, P[k].y, P[k].z, P[k].w};
        #pragma unroll
        for (int c = 0; c < 4; ++c) {
            const float x  = (gs[c] - mu) * invs;
            const float r  = __expf(ls[c] - ps[c]);
            const float rc = fminf(fmaxf(r, 0.8f), 1.2f);
            a_s += fminf(r * x, rc * x);
        }
        e_s += E[k].x + E[k].y + E[k].z + E[k].w;
    }

    double d0 = (double)a_s, d1 = (double)e_s;
    #pragma unroll
    for (int off = 32; off > 0; off >>= 1) {
        d0 += __shfl_down(d0, off, 64);
        d1 += __shfl_down(d1, off, 64);
    }
    __shared__ double sh[2][4];
    __shared__ unsigned int isLast;
    const int wid = threadIdx.x >> 6, lane = threadIdx.x & 63;
    if (lane == 0) { sh[0][wid] = d0; sh[1][wid] = d1; }
    __syncthreads();
    if (threadIdx.x == 0) {
        double t0s = 0, t1s = 0;
        #pragma unroll
        for (int w = 0; w < 4; ++w) { t0s += sh[0][w]; t1s += sh[1][w]; }
        atomicAdd(&acc[2], t0s);
        atomicAdd(&acc[4], t1s);
        __threadfence();                               // publish before counting
        unsigned int prev = atomicAdd(done, 1u);
        isLast = (prev == (unsigned int)gridDim.x - 1u) ? 1u : 0u;
    }
    __syncthreads();
    if (isLast && threadIdx.x == 0) {
        // atomic reads dodge any cross-XCD cache staleness
        const double a2 = atomicAdd(&acc[2], 0.0);
        const double a3 = atomicAdd(&acc[3], 0.0);
        const double a4 = atomicAdd(&acc[4], 0.0);
        out[0] = (float)(0.25 * a3 / Md - a2 / Md - 0.01 * a4 / Md);
    }
}

// ---------------------------------------------------------------------------
extern "C" void kernel_launch(void* const* d_in, const int* in_sizes, int n_in,
                              void* d_out, int out_size, void* d_ws, size_t ws_size,
                              hipStream_t stream) {
    const float* rewards     = (const float*)d_in[0];   // (T, N)
    const float* masks       = (const float*)d_in[1];   // (T+1, N)
    const float* bad_masks   = (const float*)d_in[2];   // (T+1, N)
    const float* value_preds = (const float*)d_in[3];   // (T+1, N)
    const float* last_value  = (const float*)d_in[4];   // (N,)
    const float* log_prob    = (const float*)d_in[5];   // (T, N)
    const float* prev_lp     = (const float*)d_in[6];   // (T, N)
    const float* new_value   = (const float*)d_in[7];   // (T, N)
    const float* dist_ent    = (const float*)d_in[8];   // (T, N)

    char* ws = (char*)d_ws;
    double* acc = (double*)ws;
    unsigned int* done = (unsigned int*)(ws + 64);
    unsigned short* b16 = (unsigned short*)(ws + 512);
    float* A = (float*)(ws + 512 + (size_t)M_TOT * 2);
    float* B = (float*)(ws + 512 + (size_t)M_TOT * 2 + (size_t)C_CHUNKS * N_DIM * 4);

    k_prep<<<STREAM_GRID, 256, 0, stream>>>((const float4*)rewards,
                                            (const float4*)masks,
                                            (const float4*)bad_masks,
                                            (const float4*)value_preds,
                                            (const float4*)last_value,
                                            (ushort4*)b16, acc, done);
    k_chunk<<<(C_CHUNKS * NV4) / 256, 256, 0, stream>>>((const ushort4*)b16,
                                                        (float4*)A, (float4*)B);
    k_ginc<<<N_DIM / 256, 256, 0, stream>>>(A, B, A /* g_in aliases A */);
    k_gae<<<(C_CHUNKS * NV4) / 256, 256, 0, stream>>>((ushort4*)b16,
                                                      (const float4*)A /* g_in */,
                                                      (const float4*)value_preds,
                                                      (const float4*)new_value,
                                                      acc);
    k_loss<<<STREAM_GRID, 256, 0, stream>>>((const ushort4*)b16 /* gae16 */,
                                            (const float4*)log_prob,
                                            (const float4*)prev_lp,
                                            (const float4*)dist_ent,
                                            acc, done, (float*)d_out);
}